// Round 5
// baseline (62.012 us; speedup 1.0000x reference)
//
#include <hip/hip_runtime.h>

#define NEG_INF (-1e30f)

static constexpr int Bn = 64;
static constexpr int Sn = 512;
static constexpr int Hn = 768;
static constexpr int Tn = 9;
static constexpr int KC = 32;       // 32 chunks of 16 steps: chunk c = steps [16c, 16c+15], t=0 flagged off
static constexpr int PSTRIDE = 108; // 9 cols * 12 padded rows
static constexpr int TPAD = 20;     // tile row stride in floats (16B-aligned, bank-spreading)

__device__ __forceinline__ float dot4(float4 a, float4 b) {
    return a.x * b.x + a.y * b.y + a.z * b.z + a.w * b.w;
}

// Fused kernel: 512 blocks x 512 threads (8 waves).
// Block -> 64 consecutive rows: b = blk>>3, s in [(blk&7)*64, +64).
// Phase 1 (emissions): wave w owns H-slice [96w, 96w+96), 6 subtiles of 16 cols.
//   Reg-staged pipeline: issue next subtile's 4 coalesced float4 loads, compute
//   current from LDS tile (lane = row, private acc[9], no cross-lane ops),
//   then ds_write the arrived next tile. W read via wave-uniform s_loads.
// Phase 2: reduce 8 wave-partials -> em_s (+bias+relu); wave-pair (2 waves)
//   per 16-step chunk builds the 9x9 log-semiring matrix + numerator partials.
__global__ __launch_bounds__(512, 4) void fused_kernel(
        const float* __restrict__ emb, const float* __restrict__ Wm,
        const float* __restrict__ bias, const float* __restrict__ trans,
        const int* __restrict__ labels, const int* __restrict__ mask,
        float* __restrict__ chunkP, float* __restrict__ auxN,
        int* __restrict__ auxC, float* __restrict__ emRow0) {
    const int blk  = blockIdx.x;
    const int tid  = threadIdx.x;
    const int lane = tid & 63;
    const int seg  = __builtin_amdgcn_readfirstlane(tid >> 6);   // wave id 0..7 (SGPR)

    __shared__ float tileU[8][64 * TPAD];   // 40 KiB; per-wave tile, reused for partials
    __shared__ float em_s[64][10];
    __shared__ float tr_s[81];

    const int rowBase = blk * 64;
    const float4* eg = (const float4*)emb;

    // prologue: issue subtile-0 loads early (in flight during tr_s staging)
    float4 stg[4];
#pragma unroll
    for (int j = 0; j < 4; ++j) {
        int z = j * 64 + lane, r = z >> 2, c4 = z & 3;
        stg[j] = eg[(size_t)(rowBase + r) * 192 + seg * 24 + c4];
    }
    if (tid < 81) tr_s[tid] = trans[tid];

    float* tile = &tileU[seg][0];
#pragma unroll
    for (int j = 0; j < 4; ++j) {
        int z = j * 64 + lane, r = z >> 2, c4 = z & 3;
        *(float4*)&tile[r * TPAD + c4 * 4] = stg[j];
    }

    float acc[Tn];
#pragma unroll
    for (int t = 0; t < Tn; ++t) acc[t] = 0.0f;

#pragma unroll
    for (int sb = 0; sb < 6; ++sb) {
        float4 nst[4];
        if (sb < 5) {   // issue next subtile's loads before current compute
#pragma unroll
            for (int j = 0; j < 4; ++j) {
                int z = j * 64 + lane, r = z >> 2, c4 = z & 3;
                nst[j] = eg[(size_t)(rowBase + r) * 192 + seg * 24 + (sb + 1) * 4 + c4];
            }
        }
        // compute current subtile: lane's own row, W via uniform s_loads
#pragma unroll
        for (int c4 = 0; c4 < 4; ++c4) {
            float4 e = *(const float4*)&tile[lane * TPAD + c4 * 4];
#pragma unroll
            for (int t = 0; t < Tn; ++t) {
                const float* wp = Wm + t * Hn + seg * 96 + sb * 16 + c4 * 4;
                float4 wv = *(const float4*)wp;   // wave-uniform -> scalar load
                acc[t] += dot4(e, wv);
            }
        }
        if (sb < 5) {   // in-order DS: writes ordered after this subtile's reads
#pragma unroll
            for (int j = 0; j < 4; ++j) {
                int z = j * 64 + lane, r = z >> 2, c4 = z & 3;
                *(float4*)&tile[r * TPAD + c4 * 4] = nst[j];
            }
        }
    }

    // per-wave partials into own tile region (no cross-wave hazard)
#pragma unroll
    for (int t = 0; t < Tn; ++t) tileU[seg][lane * Tn + t] = acc[t];
    __syncthreads();

    // reduce partials -> em_s (+bias, relu); emit row-0 emissions per batch
    for (int o = tid; o < 64 * Tn; o += 512) {
        int r = o / Tn, t = o - r * Tn;
        float s = 0.0f;
#pragma unroll
        for (int sg = 0; sg < 8; ++sg) s += tileU[sg][o];
        float v = fmaxf(s + bias[t], 0.0f);
        em_s[r][t] = v;
        if ((blk & 7) == 0 && r == 0) emRow0[(blk >> 3) * Tn + t] = v;
    }
    __syncthreads();

    // ---- phase 2: chunk scan. wave-pair (h = w&1) per chunk cl = w>>1.
    const int w  = tid >> 6;
    const int h  = w & 1;
    const int cl = w >> 1;                 // 0..3
    const int b  = blk >> 3;
    const int sc = (blk & 7) * 4 + cl;     // global chunk 0..31
    const int s0 = (blk & 7) * 64;

    const int u16 = lane & 15;
    const int tstep = s0 + cl * 16 + u16;
    int lb = 0, on = 0;
    if (lane < 16) {
        lb = labels[b * Sn + tstep];
        int mm = mask[b * Sn + tstep];
        on = (tstep >= 1) && (mm != 0) && (lb != -100);
    }
    unsigned long long bm = __ballot(on != 0);

    if (h == 0) {   // numerator + count partials for this chunk
        float np = 0.0f;
        int c1 = 0;
        if (lane < 16 && on) {
            int lpr = labels[b * Sn + tstep - 1];
            lpr = (lpr == -100) ? 0 : lpr;
            np = em_s[cl * 16 + u16][lb] + tr_s[lpr * Tn + lb];
            c1 = 1;
        }
#pragma unroll
        for (int off = 8; off; off >>= 1) {
            np += __shfl_xor(np, off);
            c1 += __shfl_xor(c1, off);
        }
        if (lane == 0) { auxN[b * KC + sc] = np; auxC[b * KC + sc] = c1; }
    }

    // 9 basis row-vectors split across the wave pair:
    // h==0: rows 0..4 on lanes 0..44; h==1: rows 5..8 on lanes 0..35
    const int v  = lane / 9;
    const int jj = lane - v * 9;
    const bool act = lane < (h ? 36 : 45);
    const int rid = h ? (5 + v) : v;

    float c[Tn];
#pragma unroll
    for (int kk = 0; kk < Tn; ++kk) c[kk] = tr_s[kk * Tn + jj];

    float pv = (act && rid == jj) ? 0.0f : NEG_INF;

    for (int u = 0; u < 16; ++u) {
        if (!((bm >> u) & 1ull)) continue;   // wave-uniform (SGPR ballot)
        float x[Tn];
#pragma unroll
        for (int kk = 0; kk < Tn; ++kk) {
            float a = __shfl(pv, (v * Tn + kk) & 63);
            x[kk] = a + c[kk];
        }
        float mx = x[0];
#pragma unroll
        for (int kk = 1; kk < Tn; ++kk) mx = fmaxf(mx, x[kk]);
        float s = 0.0f;
#pragma unroll
        for (int kk = 0; kk < Tn; ++kk) s += __expf(x[kk] - mx);
        float nv = mx + __logf(s) + em_s[cl * 16 + u][jj];
        pv = act ? nv : pv;
    }
    if (act) chunkP[(size_t)(b * KC + sc) * PSTRIDE + jj * 12 + rid] = pv;
}

// Combine per batch: one wave. alpha chain over 32 chunk matrices + denom + nll
__global__ __launch_bounds__(64) void combine_kernel(
        const float* __restrict__ emRow0, const float* __restrict__ startT,
        const float* __restrict__ endT, const int* __restrict__ labels,
        const int* __restrict__ mask, const float* __restrict__ chunkP,
        const float* __restrict__ auxN, const int* __restrict__ auxC,
        float* __restrict__ nll) {
    const int b = blockIdx.x;
    const int lane = threadIdx.x;

    float em0 = (lane < Tn) ? emRow0[b * Tn + lane] : NEG_INF;
    float alpha = (lane < Tn) ? (startT[lane] + em0) : NEG_INF;

    int lab0r = labels[b * Sn];
    int lab0 = (lab0r == -100) ? 0 : lab0r;
    float first = startT[lab0] + __shfl(em0, lab0);

    float numP = (lane < KC) ? auxN[b * KC + lane] : 0.0f;
    int   cntP = (lane < KC) ? auxC[b * KC + lane] : 0;
#pragma unroll
    for (int off = 32; off; off >>= 1) {
        numP += __shfl_xor(numP, off);
        cntP += __shfl_xor(cntP, off);
    }
    int m0 = ((mask[b * Sn] != 0) && (lab0r != -100)) ? 1 : 0;
    int cntTot = cntP + m0;
    int lastIdx = cntTot - 1;
    if (lastIdx < 0) lastIdx = 0;
    int lastLab = labels[b * Sn + lastIdx];
    lastLab = (lastLab == -100) ? 0 : lastLab;
    float num = first + numP + endT[lastLab];

    const float* Pb = chunkP + (size_t)b * KC * PSTRIDE;
    float4 p0 = make_float4(0, 0, 0, 0), p1 = p0, p2 = p0;
    if (lane < Tn) {
        const float4* pp = (const float4*)(Pb + lane * 12);
        p0 = pp[0]; p1 = pp[1]; p2 = pp[2];
    }
    for (int k = 0; k < KC; ++k) {
        float4 q0 = p0, q1 = p1, q2 = p2;
        if (k + 1 < KC && lane < Tn) {
            const float4* pp = (const float4*)(Pb + (size_t)(k + 1) * PSTRIDE + lane * 12);
            p0 = pp[0]; p1 = pp[1]; p2 = pp[2];
        }
        float av[Tn];
#pragma unroll
        for (int i = 0; i < Tn; ++i) av[i] = __shfl(alpha, i);
        float x[Tn];
        x[0] = av[0] + q0.x; x[1] = av[1] + q0.y; x[2] = av[2] + q0.z;
        x[3] = av[3] + q0.w; x[4] = av[4] + q1.x; x[5] = av[5] + q1.y;
        x[6] = av[6] + q1.z; x[7] = av[7] + q1.w; x[8] = av[8] + q2.x;
        float mx = x[0];
#pragma unroll
        for (int i = 1; i < Tn; ++i) mx = fmaxf(mx, x[i]);
        float s = 0.0f;
#pragma unroll
        for (int i = 0; i < Tn; ++i) s += __expf(x[i] - mx);
        float na = mx + __logf(s);
        alpha = (lane < Tn) ? na : NEG_INF;
    }

    float z = (lane < Tn) ? (alpha + endT[lane]) : NEG_INF;
    float mx = z;
#pragma unroll
    for (int off = 32; off; off >>= 1) mx = fmaxf(mx, __shfl_xor(mx, off));
    float s = __expf(z - mx);
#pragma unroll
    for (int off = 32; off; off >>= 1) s += __shfl_xor(s, off);
    float denom = mx + __logf(s);

    if (lane == 0) nll[b] = denom - num;
}

__global__ __launch_bounds__(64) void mean_kernel(const float* __restrict__ nll,
        float* __restrict__ out) {
    float v = nll[threadIdx.x];
#pragma unroll
    for (int off = 32; off; off >>= 1) v += __shfl_xor(v, off);
    if (threadIdx.x == 0) out[0] = v * (1.0f / 64.0f);
}

extern "C" void kernel_launch(void* const* d_in, const int* in_sizes, int n_in,
                              void* d_out, int out_size, void* d_ws, size_t ws_size,
                              hipStream_t stream) {
    const float* emb    = (const float*)d_in[0];
    const float* Wm     = (const float*)d_in[1];
    const float* bias   = (const float*)d_in[2];
    const float* startT = (const float*)d_in[3];
    const float* trans  = (const float*)d_in[4];
    const float* endT   = (const float*)d_in[5];
    const int*   labels = (const int*)d_in[6];
    const int*   mask   = (const int*)d_in[7];

    float* chunkP = (float*)d_ws;                        // B*KC*108 floats
    float* auxN   = chunkP + (size_t)Bn * KC * PSTRIDE;  // B*KC floats
    int*   auxC   = (int*)(auxN + (size_t)Bn * KC);      // B*KC ints
    float* nll    = (float*)(auxC + (size_t)Bn * KC);    // B floats
    float* emRow0 = nll + Bn;                            // B*9 floats
    float* out    = (float*)d_out;

    fused_kernel<<<512, 512, 0, stream>>>(emb, Wm, bias, trans, labels, mask,
                                          chunkP, auxN, auxC, emRow0);
    combine_kernel<<<Bn, 64, 0, stream>>>(emRow0, startT, endT, labels, mask,
                                          chunkP, auxN, auxC, nll);
    mean_kernel<<<1, 64, 0, stream>>>(nll, out);
}

// Round 6
// 55.934 us; speedup vs baseline: 1.1087x; 1.1087x over previous
//
#include <hip/hip_runtime.h>

#define NEG_INF (-1e30f)

static constexpr int Bn = 64;
static constexpr int Sn = 512;
static constexpr int Hn = 768;
static constexpr int Tn = 9;
static constexpr int KC = 32;       // 32 chunks of 16 steps; t=0 flagged off in chunk 0
static constexpr int PSTRIDE = 108; // 9 cols * 12 padded rows

typedef __attribute__((ext_vector_type(8))) short short8;
typedef __attribute__((ext_vector_type(4))) float f32x4;

__device__ __forceinline__ short f2bf(float x) {
    __bf16 h = (__bf16)x;
    return __builtin_bit_cast(short, h);
}

__device__ __forceinline__ short8 pack_bf16x8(float4 a, float4 b) {
    short8 r;
    r[0] = f2bf(a.x); r[1] = f2bf(a.y); r[2] = f2bf(a.z); r[3] = f2bf(a.w);
    r[4] = f2bf(b.x); r[5] = f2bf(b.y); r[6] = f2bf(b.z); r[7] = f2bf(b.w);
    return r;
}

// Fused kernel: 512 blocks x 512 threads (8 waves). Block owns 64 consecutive
// rows (b = blk>>3, s0 = (blk&7)*64).
// Phase 1 (emissions, bf16 MFMA): wave w -> tile (w&3, 16 rows) x K-half
// (w>>2). W held entirely in 48 VGPRs as B-fragments (lane t=l&15, zero-padded
// t>=9). A-fragments straight from global (16B/lane, wave covers 16 full
// 128B row segments), cvt to bf16, 12 x mfma_f32_16x16x32_bf16, prefetch d=4.
// C layout (m89): col=lane&15, row=(lane>>4)*4+reg -> partials to LDS,
// reduce(+bias, relu) -> em_s.
// Phase 2: wave-pair per 16-step chunk builds 9x9 log-semiring matrix +
// numerator partials (validated round-5 structure).
__global__ __launch_bounds__(512, 4) void fused_kernel(
        const float* __restrict__ emb, const float* __restrict__ Wm,
        const float* __restrict__ bias, const float* __restrict__ trans,
        const int* __restrict__ labels, const int* __restrict__ mask,
        float* __restrict__ chunkP, float* __restrict__ auxN,
        int* __restrict__ auxC, float* __restrict__ emRow0) {
    const int blk  = blockIdx.x;
    const int tid  = threadIdx.x;
    const int lane = tid & 63;
    const int wv   = tid >> 6;        // 0..7
    const int tile = wv & 3;          // 16-row tile within block
    const int kh   = wv >> 2;         // K-half: 0 -> k 0..383, 1 -> 384..767

    __shared__ float emH[2][64][10];  // per-K-half partials
    __shared__ float em_s[64][10];
    __shared__ float tr_s[81];

    if (tid < 81) tr_s[tid] = trans[tid];

    const int t9 = lane & 15;         // MFMA col (W row t), valid t9 < 9
    const int kg = lane >> 4;         // k-group 0..3 (8 consecutive k each)

    // ---- W B-fragments: whole K-half in registers (12 x short8 = 48 VGPR)
    short8 wf[12];
    {
        const float* wrow = Wm + t9 * Hn + kh * 384 + kg * 8;
#pragma unroll
        for (int s = 0; s < 12; ++s) {
            if (t9 < Tn) {
                float4 w0 = *(const float4*)(wrow + s * 32);
                float4 w1 = *(const float4*)(wrow + s * 32 + 4);
                wf[s] = pack_bf16x8(w0, w1);
            } else {
                short8 z = {0, 0, 0, 0, 0, 0, 0, 0};
                wf[s] = z;
            }
        }
    }

    // ---- A stream + MFMA, prefetch depth 4
    const int rowBase = blk * 64;
    const float* arow = emb + (size_t)(rowBase + tile * 16 + t9) * Hn
                        + kh * 384 + kg * 8;
    float4 pf0[4], pf1[4];
#pragma unroll
    for (int d = 0; d < 4; ++d) {
        pf0[d] = *(const float4*)(arow + d * 32);
        pf1[d] = *(const float4*)(arow + d * 32 + 4);
    }
    f32x4 acc = {0.0f, 0.0f, 0.0f, 0.0f};
#pragma unroll
    for (int s = 0; s < 12; ++s) {
        float4 a0 = pf0[s & 3];
        float4 a1 = pf1[s & 3];
        if (s + 4 < 12) {
            pf0[s & 3] = *(const float4*)(arow + (s + 4) * 32);
            pf1[s & 3] = *(const float4*)(arow + (s + 4) * 32 + 4);
        }
        short8 af = pack_bf16x8(a0, a1);
        acc = __builtin_amdgcn_mfma_f32_16x16x32_bf16(af, wf[s], acc, 0, 0, 0);
    }

    // ---- C writeback: col = lane&15, row = (lane>>4)*4 + r
    if (t9 < Tn) {
#pragma unroll
        for (int r = 0; r < 4; ++r)
            emH[kh][tile * 16 + kg * 4 + r][t9] = acc[r];
    }
    __syncthreads();

    // reduce K-halves (+bias, relu) -> em_s; emit row-0 emissions per batch
    for (int o = tid; o < 64 * Tn; o += 512) {
        int r = o / Tn, t = o - r * Tn;
        float v = fmaxf(emH[0][r][t] + emH[1][r][t] + bias[t], 0.0f);
        em_s[r][t] = v;
        if ((blk & 7) == 0 && r == 0) emRow0[(blk >> 3) * Tn + t] = v;
    }
    __syncthreads();

    // ---- phase 2: chunk scan. wave-pair (h = wv&1) per chunk cl = wv>>1.
    const int h  = wv & 1;
    const int cl = wv >> 1;                // 0..3
    const int b  = blk >> 3;
    const int sc = (blk & 7) * 4 + cl;     // global chunk 0..31
    const int s0 = (blk & 7) * 64;

    const int u16 = lane & 15;
    const int tstep = s0 + cl * 16 + u16;
    int lb = 0, on = 0;
    if (lane < 16) {
        lb = labels[b * Sn + tstep];
        int mm = mask[b * Sn + tstep];
        on = (tstep >= 1) && (mm != 0) && (lb != -100);
    }
    unsigned long long bm = __ballot(on != 0);

    if (h == 0) {   // numerator + count partials for this chunk
        float np = 0.0f;
        int c1 = 0;
        if (lane < 16 && on) {
            int lpr = labels[b * Sn + tstep - 1];
            lpr = (lpr == -100) ? 0 : lpr;
            np = em_s[cl * 16 + u16][lb] + tr_s[lpr * Tn + lb];
            c1 = 1;
        }
#pragma unroll
        for (int off = 8; off; off >>= 1) {
            np += __shfl_xor(np, off);
            c1 += __shfl_xor(c1, off);
        }
        if (lane == 0) { auxN[b * KC + sc] = np; auxC[b * KC + sc] = c1; }
    }

    // 9 basis row-vectors split across the wave pair:
    // h==0: rows 0..4 on lanes 0..44; h==1: rows 5..8 on lanes 0..35
    const int v  = lane / 9;
    const int jj = lane - v * 9;
    const bool act = lane < (h ? 36 : 45);
    const int rid = h ? (5 + v) : v;

    float c[Tn];
#pragma unroll
    for (int kk = 0; kk < Tn; ++kk) c[kk] = tr_s[kk * Tn + jj];

    float pv = (act && rid == jj) ? 0.0f : NEG_INF;

    for (int u = 0; u < 16; ++u) {
        if (!((bm >> u) & 1ull)) continue;   // wave-uniform (SGPR ballot)
        float x[Tn];
#pragma unroll
        for (int kk = 0; kk < Tn; ++kk) {
            float a = __shfl(pv, (v * Tn + kk) & 63);
            x[kk] = a + c[kk];
        }
        float mx = x[0];
#pragma unroll
        for (int kk = 1; kk < Tn; ++kk) mx = fmaxf(mx, x[kk]);
        float s = 0.0f;
#pragma unroll
        for (int kk = 0; kk < Tn; ++kk) s += __expf(x[kk] - mx);
        float nv = mx + __logf(s) + em_s[cl * 16 + u][jj];
        pv = act ? nv : pv;
    }
    if (act) chunkP[(size_t)(b * KC + sc) * PSTRIDE + jj * 12 + rid] = pv;
}

// Combine per batch: one wave. alpha chain over 32 chunk matrices + denom + nll
__global__ __launch_bounds__(64) void combine_kernel(
        const float* __restrict__ emRow0, const float* __restrict__ startT,
        const float* __restrict__ endT, const int* __restrict__ labels,
        const int* __restrict__ mask, const float* __restrict__ chunkP,
        const float* __restrict__ auxN, const int* __restrict__ auxC,
        float* __restrict__ nll) {
    const int b = blockIdx.x;
    const int lane = threadIdx.x;

    float em0 = (lane < Tn) ? emRow0[b * Tn + lane] : NEG_INF;
    float alpha = (lane < Tn) ? (startT[lane] + em0) : NEG_INF;

    int lab0r = labels[b * Sn];
    int lab0 = (lab0r == -100) ? 0 : lab0r;
    float first = startT[lab0] + __shfl(em0, lab0);

    float numP = (lane < KC) ? auxN[b * KC + lane] : 0.0f;
    int   cntP = (lane < KC) ? auxC[b * KC + lane] : 0;
#pragma unroll
    for (int off = 32; off; off >>= 1) {
        numP += __shfl_xor(numP, off);
        cntP += __shfl_xor(cntP, off);
    }
    int m0 = ((mask[b * Sn] != 0) && (lab0r != -100)) ? 1 : 0;
    int cntTot = cntP + m0;
    int lastIdx = cntTot - 1;
    if (lastIdx < 0) lastIdx = 0;
    int lastLab = labels[b * Sn + lastIdx];
    lastLab = (lastLab == -100) ? 0 : lastLab;
    float num = first + numP + endT[lastLab];

    const float* Pb = chunkP + (size_t)b * KC * PSTRIDE;
    float4 p0 = make_float4(0, 0, 0, 0), p1 = p0, p2 = p0;
    if (lane < Tn) {
        const float4* pp = (const float4*)(Pb + lane * 12);
        p0 = pp[0]; p1 = pp[1]; p2 = pp[2];
    }
    for (int k = 0; k < KC; ++k) {
        float4 q0 = p0, q1 = p1, q2 = p2;
        if (k + 1 < KC && lane < Tn) {
            const float4* pp = (const float4*)(Pb + (size_t)(k + 1) * PSTRIDE + lane * 12);
            p0 = pp[0]; p1 = pp[1]; p2 = pp[2];
        }
        float av[Tn];
#pragma unroll
        for (int i = 0; i < Tn; ++i) av[i] = __shfl(alpha, i);
        float x[Tn];
        x[0] = av[0] + q0.x; x[1] = av[1] + q0.y; x[2] = av[2] + q0.z;
        x[3] = av[3] + q0.w; x[4] = av[4] + q1.x; x[5] = av[5] + q1.y;
        x[6] = av[6] + q1.z; x[7] = av[7] + q1.w; x[8] = av[8] + q2.x;
        float mx = x[0];
#pragma unroll
        for (int i = 1; i < Tn; ++i) mx = fmaxf(mx, x[i]);
        float s = 0.0f;
#pragma unroll
        for (int i = 0; i < Tn; ++i) s += __expf(x[i] - mx);
        float na = mx + __logf(s);
        alpha = (lane < Tn) ? na : NEG_INF;
    }

    float z = (lane < Tn) ? (alpha + endT[lane]) : NEG_INF;
    float mx = z;
#pragma unroll
    for (int off = 32; off; off >>= 1) mx = fmaxf(mx, __shfl_xor(mx, off));
    float s = __expf(z - mx);
#pragma unroll
    for (int off = 32; off; off >>= 1) s += __shfl_xor(s, off);
    float denom = mx + __logf(s);

    if (lane == 0) nll[b] = denom - num;
}

__global__ __launch_bounds__(64) void mean_kernel(const float* __restrict__ nll,
        float* __restrict__ out) {
    float v = nll[threadIdx.x];
#pragma unroll
    for (int off = 32; off; off >>= 1) v += __shfl_xor(v, off);
    if (threadIdx.x == 0) out[0] = v * (1.0f / 64.0f);
}

extern "C" void kernel_launch(void* const* d_in, const int* in_sizes, int n_in,
                              void* d_out, int out_size, void* d_ws, size_t ws_size,
                              hipStream_t stream) {
    const float* emb    = (const float*)d_in[0];
    const float* Wm     = (const float*)d_in[1];
    const float* bias   = (const float*)d_in[2];
    const float* startT = (const float*)d_in[3];
    const float* trans  = (const float*)d_in[4];
    const float* endT   = (const float*)d_in[5];
    const int*   labels = (const int*)d_in[6];
    const int*   mask   = (const int*)d_in[7];

    float* chunkP = (float*)d_ws;                        // B*KC*108 floats
    float* auxN   = chunkP + (size_t)Bn * KC * PSTRIDE;  // B*KC floats
    int*   auxC   = (int*)(auxN + (size_t)Bn * KC);      // B*KC ints
    float* nll    = (float*)(auxC + (size_t)Bn * KC);    // B floats
    float* emRow0 = nll + Bn;                            // B*9 floats
    float* out    = (float*)d_out;

    fused_kernel<<<512, 512, 0, stream>>>(emb, Wm, bias, trans, labels, mask,
                                          chunkP, auxN, auxC, emRow0);
    combine_kernel<<<Bn, 64, 0, stream>>>(emRow0, startT, endT, labels, mask,
                                          chunkP, auxN, auxC, nll);
    mean_kernel<<<1, 64, 0, stream>>>(nll, out);
}

// Round 7
// 55.690 us; speedup vs baseline: 1.1135x; 1.0044x over previous
//
#include <hip/hip_runtime.h>

#define NEG_INF (-1e30f)

static constexpr int Bn = 64;
static constexpr int Sn = 512;
static constexpr int Hn = 768;
static constexpr int Tn = 9;
static constexpr int KC = 32;       // 32 chunks of 16 steps; t=0 flagged off in chunk 0
static constexpr int PSTRIDE = 108; // 9 cols * 12 padded rows
static constexpr int RB = 32;       // rows per block
static constexpr int BK = 128;      // K-chunk in floats (6 steps of 128 = 768)

typedef __attribute__((ext_vector_type(8))) short short8;
typedef __attribute__((ext_vector_type(4))) float f32x4;

__device__ __forceinline__ short f2bf(float x) {
    __bf16 h = (__bf16)x;
    return __builtin_bit_cast(short, h);
}

__device__ __forceinline__ short8 pack_bf16x8(float4 a, float4 b) {
    short8 r;
    r[0] = f2bf(a.x); r[1] = f2bf(a.y); r[2] = f2bf(a.z); r[3] = f2bf(a.w);
    r[4] = f2bf(b.x); r[5] = f2bf(b.y); r[6] = f2bf(b.z); r[7] = f2bf(b.w);
    return r;
}

__device__ __forceinline__ void gll16(const float* g, float* l) {
    __builtin_amdgcn_global_load_lds(
        (const __attribute__((address_space(1))) void*)g,
        (__attribute__((address_space(3))) void*)l, 16, 0, 0);
}

// Fused kernel: 1024 blocks x 256 threads (4 waves). Block owns 32 rows
// (b = blk>>4, s0 = (blk&15)*32).
// Phase 1 (emissions GEMM): per K-step (BK=128), stage a 32x128 f32 tile via
// global_load_lds width=16 (LDS linear [32][128], SOURCE pre-XOR-swizzled so
// ds_read_b128 A-fragments are bank-conflict-free). Wave wv: tile tl=wv&1
// (16 rows) x K-half kh=wv>>1 (64 floats of each chunk) -> 2 MFMA/step.
// W held in 48 VGPRs as bf16 B-fragments (round-6-verified layout).
// Phase 2: wave-pair per 16-step chunk: 9x9 log-semiring matrix + numerator
// partials (round-5/6-validated structure).
__global__ __launch_bounds__(256, 4) void fused_kernel(
        const float* __restrict__ emb, const float* __restrict__ Wm,
        const float* __restrict__ bias, const float* __restrict__ trans,
        const int* __restrict__ labels, const int* __restrict__ mask,
        float* __restrict__ chunkP, float* __restrict__ auxN,
        int* __restrict__ auxC, float* __restrict__ emRow0) {
    const int blk  = blockIdx.x;
    const int tid  = threadIdx.x;
    const int lane = tid & 63;
    const int wv   = tid >> 6;        // 0..3
    const int tl   = wv & 1;          // 16-row tile
    const int kh   = wv >> 1;         // K-half of each 128-chunk

    __shared__ float Ast[RB * BK];    // 16 KB staging tile (single buffer)
    __shared__ float emH[2][RB][10];
    __shared__ float em_s[RB][10];
    __shared__ float tr_s[81];

    if (tid < 81) tr_s[tid] = trans[tid];

    const int t9 = lane & 15;         // A row within tile / W row t
    const int kg = lane >> 4;         // k-group (8 consecutive k)

    // ---- W B-fragments: 12 x short8 = 48 VGPR (k = s*128 + kh*64 + m*32 + kg*8)
    short8 wf[12];
#pragma unroll
    for (int s = 0; s < 6; ++s) {
#pragma unroll
        for (int m = 0; m < 2; ++m) {
            if (t9 < Tn) {
                const float* wp = Wm + t9 * Hn + s * 128 + kh * 64 + m * 32 + kg * 8;
                float4 w0 = *(const float4*)wp;
                float4 w1 = *(const float4*)(wp + 4);
                wf[s * 2 + m] = pack_bf16x8(w0, w1);
            } else {
                short8 z = {0, 0, 0, 0, 0, 0, 0, 0};
                wf[s * 2 + m] = z;
            }
        }
    }

    // ---- staging address precompute: thread's 4 slots (16B each)
    // slot L = tid + j*256: r = L>>5, ls = L&31; source col-slot = ls ^ (r&7)
    int goff[4];   // float offset within block's row-panel, per j (k0 added per step)
#pragma unroll
    for (int j = 0; j < 4; ++j) {
        int L = tid + j * 256;
        int r = L >> 5, ls = L & 31;
        goff[j] = r * Hn + ((ls ^ (r & 7)) << 2);
    }
    const float* gbase = emb + (size_t)blk * RB * Hn;

    // ---- K-loop: stage (DMA) -> barrier -> ds_read + MFMA
    const int rA   = tl * 16 + t9;          // A row in tile
    const int rx   = rA & 7;
    f32x4 acc = {0.0f, 0.0f, 0.0f, 0.0f};
    for (int s = 0; s < 6; ++s) {
        if (s) __syncthreads();             // previous compute done before overwrite
#pragma unroll
        for (int j = 0; j < 4; ++j)
            gll16(gbase + goff[j] + s * BK, &Ast[(j * 256 + wv * 64) * 4]);
        asm volatile("s_waitcnt vmcnt(0)" ::: "memory");
        __syncthreads();
#pragma unroll
        for (int m = 0; m < 2; ++m) {
            int c4 = kh * 16 + m * 8 + kg * 2;          // global 16B-slot in chunk
            float4 a0 = *(const float4*)&Ast[(rA * 32 + (c4 ^ rx)) * 4];
            float4 a1 = *(const float4*)&Ast[(rA * 32 + ((c4 + 1) ^ rx)) * 4];
            short8 af = pack_bf16x8(a0, a1);
            acc = __builtin_amdgcn_mfma_f32_16x16x32_bf16(af, wf[s * 2 + m], acc, 0, 0, 0);
        }
    }

    // ---- C writeback (round-6-verified layout): col=t9, row=kg*4+r
    if (t9 < Tn) {
#pragma unroll
        for (int r = 0; r < 4; ++r)
            emH[kh][tl * 16 + kg * 4 + r][t9] = acc[r];
    }
    __syncthreads();

    // reduce K-halves (+bias, relu) -> em_s; emit row-0 emissions per batch
    for (int o = tid; o < RB * Tn; o += 256) {
        int r = o / Tn, t = o - r * Tn;
        float v = fmaxf(emH[0][r][t] + emH[1][r][t] + bias[t], 0.0f);
        em_s[r][t] = v;
        if ((blk & 15) == 0 && r == 0) emRow0[(blk >> 4) * Tn + t] = v;
    }
    __syncthreads();

    // ---- phase 2: chunk scan. wave-pair (h = wv&1) per chunk cl = wv>>1.
    const int h  = wv & 1;
    const int cl = wv >> 1;                // 0..1
    const int b  = blk >> 4;
    const int sc = (blk & 15) * 2 + cl;    // global chunk 0..31
    const int s0 = (blk & 15) * 32;

    const int u16 = lane & 15;
    const int tstep = s0 + cl * 16 + u16;
    int lb = 0, on = 0;
    if (lane < 16) {
        lb = labels[b * Sn + tstep];
        int mm = mask[b * Sn + tstep];
        on = (tstep >= 1) && (mm != 0) && (lb != -100);
    }
    unsigned long long bm = __ballot(on != 0);

    if (h == 0) {   // numerator + count partials for this chunk
        float np = 0.0f;
        int c1 = 0;
        if (lane < 16 && on) {
            int lpr = labels[b * Sn + tstep - 1];
            lpr = (lpr == -100) ? 0 : lpr;
            np = em_s[cl * 16 + u16][lb] + tr_s[lpr * Tn + lb];
            c1 = 1;
        }
#pragma unroll
        for (int off = 8; off; off >>= 1) {
            np += __shfl_xor(np, off);
            c1 += __shfl_xor(c1, off);
        }
        if (lane == 0) { auxN[b * KC + sc] = np; auxC[b * KC + sc] = c1; }
    }

    // 9 basis row-vectors split across the wave pair:
    // h==0: rows 0..4 on lanes 0..44; h==1: rows 5..8 on lanes 0..35
    const int v  = lane / 9;
    const int jj = lane - v * 9;
    const bool act = lane < (h ? 36 : 45);
    const int rid = h ? (5 + v) : v;

    float c[Tn];
#pragma unroll
    for (int kk = 0; kk < Tn; ++kk) c[kk] = tr_s[kk * Tn + jj];

    float pv = (act && rid == jj) ? 0.0f : NEG_INF;

    for (int u = 0; u < 16; ++u) {
        if (!((bm >> u) & 1ull)) continue;   // wave-uniform (SGPR ballot)
        float x[Tn];
#pragma unroll
        for (int kk = 0; kk < Tn; ++kk) {
            float a = __shfl(pv, (v * Tn + kk) & 63);
            x[kk] = a + c[kk];
        }
        float mx = x[0];
#pragma unroll
        for (int kk = 1; kk < Tn; ++kk) mx = fmaxf(mx, x[kk]);
        float s = 0.0f;
#pragma unroll
        for (int kk = 0; kk < Tn; ++kk) s += __expf(x[kk] - mx);
        float nv = mx + __logf(s) + em_s[cl * 16 + u][jj];
        pv = act ? nv : pv;
    }
    if (act) chunkP[(size_t)(b * KC + sc) * PSTRIDE + jj * 12 + rid] = pv;
}

// Combine per batch: one wave. alpha chain over 32 chunk matrices + denom + nll
__global__ __launch_bounds__(64) void combine_kernel(
        const float* __restrict__ emRow0, const float* __restrict__ startT,
        const float* __restrict__ endT, const int* __restrict__ labels,
        const int* __restrict__ mask, const float* __restrict__ chunkP,
        const float* __restrict__ auxN, const int* __restrict__ auxC,
        float* __restrict__ nll) {
    const int b = blockIdx.x;
    const int lane = threadIdx.x;

    float em0 = (lane < Tn) ? emRow0[b * Tn + lane] : NEG_INF;
    float alpha = (lane < Tn) ? (startT[lane] + em0) : NEG_INF;

    int lab0r = labels[b * Sn];
    int lab0 = (lab0r == -100) ? 0 : lab0r;
    float first = startT[lab0] + __shfl(em0, lab0);

    float numP = (lane < KC) ? auxN[b * KC + lane] : 0.0f;
    int   cntP = (lane < KC) ? auxC[b * KC + lane] : 0;
#pragma unroll
    for (int off = 32; off; off >>= 1) {
        numP += __shfl_xor(numP, off);
        cntP += __shfl_xor(cntP, off);
    }
    int m0 = ((mask[b * Sn] != 0) && (lab0r != -100)) ? 1 : 0;
    int cntTot = cntP + m0;
    int lastIdx = cntTot - 1;
    if (lastIdx < 0) lastIdx = 0;
    int lastLab = labels[b * Sn + lastIdx];
    lastLab = (lastLab == -100) ? 0 : lastLab;
    float num = first + numP + endT[lastLab];

    const float* Pb = chunkP + (size_t)b * KC * PSTRIDE;
    float4 p0 = make_float4(0, 0, 0, 0), p1 = p0, p2 = p0;
    if (lane < Tn) {
        const float4* pp = (const float4*)(Pb + lane * 12);
        p0 = pp[0]; p1 = pp[1]; p2 = pp[2];
    }
    for (int k = 0; k < KC; ++k) {
        float4 q0 = p0, q1 = p1, q2 = p2;
        if (k + 1 < KC && lane < Tn) {
            const float4* pp = (const float4*)(Pb + (size_t)(k + 1) * PSTRIDE + lane * 12);
            p0 = pp[0]; p1 = pp[1]; p2 = pp[2];
        }
        float av[Tn];
#pragma unroll
        for (int i = 0; i < Tn; ++i) av[i] = __shfl(alpha, i);
        float x[Tn];
        x[0] = av[0] + q0.x; x[1] = av[1] + q0.y; x[2] = av[2] + q0.z;
        x[3] = av[3] + q0.w; x[4] = av[4] + q1.x; x[5] = av[5] + q1.y;
        x[6] = av[6] + q1.z; x[7] = av[7] + q1.w; x[8] = av[8] + q2.x;
        float mx = x[0];
#pragma unroll
        for (int i = 1; i < Tn; ++i) mx = fmaxf(mx, x[i]);
        float s = 0.0f;
#pragma unroll
        for (int i = 0; i < Tn; ++i) s += __expf(x[i] - mx);
        float na = mx + __logf(s);
        alpha = (lane < Tn) ? na : NEG_INF;
    }

    float z = (lane < Tn) ? (alpha + endT[lane]) : NEG_INF;
    float mx = z;
#pragma unroll
    for (int off = 32; off; off >>= 1) mx = fmaxf(mx, __shfl_xor(mx, off));
    float s = __expf(z - mx);
#pragma unroll
    for (int off = 32; off; off >>= 1) s += __shfl_xor(s, off);
    float denom = mx + __logf(s);

    if (lane == 0) nll[b] = denom - num;
}

__global__ __launch_bounds__(64) void mean_kernel(const float* __restrict__ nll,
        float* __restrict__ out) {
    float v = nll[threadIdx.x];
#pragma unroll
    for (int off = 32; off; off >>= 1) v += __shfl_xor(v, off);
    if (threadIdx.x == 0) out[0] = v * (1.0f / 64.0f);
}

extern "C" void kernel_launch(void* const* d_in, const int* in_sizes, int n_in,
                              void* d_out, int out_size, void* d_ws, size_t ws_size,
                              hipStream_t stream) {
    const float* emb    = (const float*)d_in[0];
    const float* Wm     = (const float*)d_in[1];
    const float* bias   = (const float*)d_in[2];
    const float* startT = (const float*)d_in[3];
    const float* trans  = (const float*)d_in[4];
    const float* endT   = (const float*)d_in[5];
    const int*   labels = (const int*)d_in[6];
    const int*   mask   = (const int*)d_in[7];

    float* chunkP = (float*)d_ws;                        // B*KC*108 floats
    float* auxN   = chunkP + (size_t)Bn * KC * PSTRIDE;  // B*KC floats
    int*   auxC   = (int*)(auxN + (size_t)Bn * KC);      // B*KC ints
    float* nll    = (float*)(auxC + (size_t)Bn * KC);    // B floats
    float* emRow0 = nll + Bn;                            // B*9 floats
    float* out    = (float*)d_out;

    fused_kernel<<<Bn * Sn / RB, 256, 0, stream>>>(emb, Wm, bias, trans,
                                                   labels, mask, chunkP,
                                                   auxN, auxC, emRow0);
    combine_kernel<<<Bn, 64, 0, stream>>>(emRow0, startT, endT, labels, mask,
                                          chunkP, auxN, auxC, nll);
    mean_kernel<<<1, 64, 0, stream>>>(nll, out);
}